// Round 14
// baseline (214.421 us; speedup 1.0000x reference)
//
#include <hip/hip_runtime.h>
#include <hip/hip_bf16.h>

#define Dd   64
#define BWk  31
#define NTH  256
#define CS   256                // pass-buffer per-col stride (shorts): 8 n x 32 k
#define RS   64                 // result-tile row stride (floats)

typedef float  f32x4   __attribute__((ext_vector_type(4)));
typedef short  bf16x8  __attribute__((ext_vector_type(8)));
typedef float  float4a __attribute__((ext_vector_type(4), aligned(4)));

__device__ __forceinline__ unsigned pk2(float lo, float hi) {
    __hip_bfloat162 h = __float22bfloat162_rn(make_float2(lo, hi));
    union { __hip_bfloat162 h; unsigned u; } c; c.h = h; return c.u;
}

// barrier that only waits for LDS ops (NOT the global store / load queues).
__device__ __forceinline__ void lds_barrier() {
    asm volatile("s_waitcnt lgkmcnt(0)" ::: "memory");
    __builtin_amdgcn_s_barrier();
    __builtin_amdgcn_sched_barrier(0);
}

__global__ __launch_bounds__(NTH, 6)
void band_mfma(const float* __restrict__ pw,
               const float* __restrict__ x,
               float* __restrict__ out)
{
    // pass-shared y-interp weight buffer: [c=18][n_l=8][k=32 (k31=0)] bf16
    __shared__ unsigned short wYb[18 * CS];          // 9216 B
    // double-buffered result tile: [32 n][64 px], row stride 64
    __shared__ float tile[2][32 * RS];               // 2 x 8192 B (total 25600 B)

    const int tid = threadIdx.x;
    const int bx  = blockIdx.x;         // 0..3  (64-px column tiles)
    const int y   = blockIdx.y;
    const int x0  = bx * 64;

    // exact scale-4 half-pixel y interpolation (validated rounds 1-13)
    const int yq = y >> 2, ry = y & 3;
    const int y0i = yq + ((ry < 2) ? -1 : 0);
    const float fy = 0.125f + 0.25f * (float)((ry + 2) & 3);
    const int y0c = (y0i < 0) ? 0 : y0i;
    const int y1c = (y0i + 1 > Dd - 1) ? Dd - 1 : (y0i + 1);
    const int cxb = (x0 >> 2) - 1;      // leftmost coarse col staged

    const int lane = tid & 63;
    const int px   = lane & 15;         // MFMA column = pixel-in-tile
    const int q    = lane >> 4;         // k-slice / C row group
    const int t    = tid >> 6;          // wave id = 16-px tile (0..3)
    const int xt0  = x0 + 16 * t;       // tile's global x base

    // ---- staged in 4 passes of 8 n through the small pass buffer ----
    // stage task: (n_l = tid>>5, c-group = (tid>>3)&3, k-quad = tid&7)
    bf16x8 A[6][2];
    {
        const int kq  = tid & 7;
        const int k0  = kq << 2;            // 0,4,...,28
        const int cg  = (tid >> 3) & 3;
        const int n_l = tid >> 5;           // 0..7
        const bool lastk = (kq == 7);
        #pragma unroll
        for (int p = 0; p < 4; ++p) {
            const int n_g = p * 8 + n_l;
            const size_t rb0 = ((size_t)n_g * 4096) * BWk + k0;
            #pragma unroll
            for (int ci = cg; ci < 18; ci += 4) {
                int cx = cxb + ci;
                cx = (cx < 0) ? 0 : ((cx > Dd - 1) ? Dd - 1 : cx);
                const size_t rb = rb0 + (size_t)cx * BWk;
                float4a a = *(const float4a*)(pw + rb + (size_t)y0c * (Dd * BWk));
                float4a b = *(const float4a*)(pw + rb + (size_t)y1c * (Dd * BWk));
                float v0 = fmaf(fy, b.x - a.x, a.x);
                float v1 = fmaf(fy, b.y - a.y, a.y);
                float v2 = fmaf(fy, b.z - a.z, a.z);
                float v3 = lastk ? 0.f : fmaf(fy, b.w - a.w, a.w);   // k=31 pad
                *(uint2*)&wYb[ci * CS + n_l * 32 + k0] =
                    make_uint2(pk2(v0, v1), pk2(v2, v3));
            }
            __syncthreads();
            // frag rows n = mh*16 + px live in pass p = 2*mh + (px>>3)
            if ((px >> 3) == (p & 1)) {
                const int mh = p >> 1;
                #pragma unroll
                for (int j = 0; j < 6; ++j)
                    A[j][mh] = *(const bf16x8*)
                        &wYb[(4 * t + j) * CS + (px & 7) * 32 + q * 8];
            }
            __syncthreads();
        }
    }

    // per-pixel x-interp coefficients c_j (2 of 6 nonzero); (xt0+px)&3 == px&3
    const int rx = px & 3;
    const float fx = 0.125f + 0.25f * (float)((rx + 2) & 3);
    const int j0 = (px >> 2) + ((rx < 2) ? 0 : 1);   // 0..4
    float c[6];
    #pragma unroll
    for (int j = 0; j < 6; ++j)
        c[j] = (j == j0) ? (1.f - fx) : ((j == j0 + 1) ? fx : 0.f);

    const int gxb = xt0 + px + q * 8 - 15;           // B element i -> x[gxb + i]
    const bool edge = (bx == 0 && t == 0) || (bx == 3 && t == 3);
    const f32x4 zero = {0.f, 0.f, 0.f, 0.f};

    // store-phase lane roles: instr s covers rows 8t+4s+rr, 16B (4 px) per lane
    const int rr = lane >> 4;           // row within the 4-row group
    const int ii = lane & 15;           // 16B chunk within the 64-px row
    const size_t sb = (size_t)y * 256 + (size_t)x0 + (size_t)(ii * 4);

    #pragma unroll 2
    for (int bc = 0; bc < 32; ++bc) {
        const float* xrow = x + ((size_t)bc * 256 + y) * 256;

        // B-frag: Hankel column px, k-slice q (direct from global, L1/L2-hot)
        float4a v0, v1;
        if (!edge) {
            v0 = *(const float4a*)(xrow + gxb);
            v1 = *(const float4a*)(xrow + gxb + 4);
        } else {
            float tv[8];
            #pragma unroll
            for (int i = 0; i < 8; ++i) {
                int gx = gxb + i;
                tv[i] = ((unsigned)gx < 256u) ? xrow[gx] : 0.f;
            }
            v0 = *(float4a*)&tv[0]; v1 = *(float4a*)&tv[4];
        }
        union { unsigned u[4]; bf16x8 v; } bb;
        bb.u[0] = pk2(v0.x, v0.y);
        bb.u[1] = pk2(v0.z, v0.w);
        bb.u[2] = pk2(v1.x, v1.y);
        bb.u[3] = pk2(v1.z, v1.w);
        const bf16x8 B = bb.v;

        float* tl = tile[bc & 1];
        #pragma unroll
        for (int mh = 0; mh < 2; ++mh) {
            f32x4 acc = zero;
            #pragma unroll
            for (int j = 0; j < 6; ++j) {
                f32x4 g = __builtin_amdgcn_mfma_f32_16x16x32_bf16(
                              A[j][mh], B, zero, 0, 0, 0);
                acc += g * c[j];               // x-interp blend, exact in f32
            }
            // C layout: col = px, row = 4q + reg -> n = mh*16 + 4q + reg
            float* w = tl + (mh * 16 + q * 4) * RS + 16 * t + px;
            w[0]      = acc.x;
            w[RS]     = acc.y;
            w[2 * RS] = acc.z;
            w[3 * RS] = acc.w;
        }
        lds_barrier();   // LDS visibility only; nt stores keep draining async

        // store phase: two dwordx4 wave-stores (rows 8t..8t+7 in 4-row groups)
        const float* ts = tile[bc & 1];
        #pragma unroll
        for (int s = 0; s < 2; ++s) {
            const int row = t * 8 + s * 4 + rr;          // n index (0..31)
            f32x4 v = *(const f32x4*)&ts[row * RS + ii * 4];
            f32x4* dst = (f32x4*)(out + (size_t)(bc * 32 + row) * 65536 + sb);
            __builtin_nontemporal_store(v, dst);
        }
    }
}

extern "C" void kernel_launch(void* const* d_in, const int* in_sizes, int n_in,
                              void* d_out, int out_size, void* d_ws, size_t ws_size,
                              hipStream_t stream) {
    const float* pw = (const float*)d_in[0];   // pre_weights [32,4096,31]
    const float* x  = (const float*)d_in[1];   // x [4,8,256,256] -> [32,256,256]
    float* out = (float*)d_out;                // [32,32,256,256] f32

    dim3 grid(4, 256, 1);
    dim3 block(NTH, 1, 1);
    band_mfma<<<grid, block, 0, stream>>>(pw, x, out);
}

// Round 15
// 70.154 us; speedup vs baseline: 3.0564x; 3.0564x over previous
//
#include <hip/hip_runtime.h>
#include <hip/hip_bf16.h>

#define Dd   64
#define BWk  31
#define NTH  256
#define NS   32                 // wYb k-stride (bf16 units): 64B rows (A-frags load once)
#define CS   (32 * NS)          // per-coarse-col stride = 1024 shorts
#define NCOL 18                 // coarse cols staged per block (64px -> 16 + 2 border)
#define RS   64                 // result-tile row stride (floats)

typedef float  f32x4   __attribute__((ext_vector_type(4)));
typedef short  bf16x8  __attribute__((ext_vector_type(8)));
typedef float  float4a __attribute__((ext_vector_type(4), aligned(4)));

__device__ __forceinline__ unsigned pk2(float lo, float hi) {
    __hip_bfloat162 h = __float22bfloat162_rn(make_float2(lo, hi));
    union { __hip_bfloat162 h; unsigned u; } c; c.h = h; return c.u;
}

// barrier that only waits for LDS ops (NOT the global store / load queues).
__device__ __forceinline__ void lds_barrier() {
    asm volatile("s_waitcnt lgkmcnt(0)" ::: "memory");
    __builtin_amdgcn_s_barrier();
    __builtin_amdgcn_sched_barrier(0);
}

__global__ __launch_bounds__(NTH, 3)
void band_mfma(const float* __restrict__ pw,
               const float* __restrict__ x,
               float* __restrict__ out)
{
    // y-interpolated coarse weights, bf16: [c=18][n=32][k=32 (k31=0)]
    __shared__ unsigned short wYb[NCOL * CS];        // 36864 B
    // double-buffered result tile: [32 n][64 px], row stride 64
    __shared__ float tile[2][32 * RS];               // 2 x 8192 B (total 53248 B)

    const int tid = threadIdx.x;

    // --- XCD y-banding swizzle (single variable vs R11) ---
    // HW round-robins linear block id over 8 XCDs. Give XCD g the contiguous
    // y-band [32g, 32g+32) with all 4 bx tiles: its x slice (1MB) and pw rows
    // (~2.3MB) become L2-resident, and its ~96 resident blocks write into the
    // same 32KB y-windows of each output plane (emergent page locality).
    const unsigned id   = blockIdx.x;        // 0..1023
    const unsigned xcd  = id & 7u;
    const unsigned slot = id >> 3;           // 0..127
    const int bx = (int)(slot >> 5);         // 0..3
    const int y  = (int)(xcd * 32u + (slot & 31u));
    const int x0 = bx * 64;

    // exact scale-4 half-pixel y interpolation (validated rounds 1-14)
    const int yq = y >> 2, ry = y & 3;
    const int y0i = yq + ((ry < 2) ? -1 : 0);
    const float fy = 0.125f + 0.25f * (float)((ry + 2) & 3);
    const int y0c = (y0i < 0) ? 0 : y0i;
    const int y1c = (y0i + 1 > Dd - 1) ? Dd - 1 : (y0i + 1);
    const int cxb = (x0 >> 2) - 1;      // leftmost coarse col staged

    // ---- stage wYb: thread task = (n = tid>>3, k0 = (tid&7)*4) over 18 cols ----
    {
        const int n  = tid >> 3;            // 0..31
        const int k0 = (tid & 7) << 2;      // 0,4,...,28
        const bool lastk = (k0 == 28);
        const size_t rb0 = ((size_t)n * 4096) * BWk + k0;
        #pragma unroll 6
        for (int i = 0; i < NCOL; ++i) {
            int cx = cxb + i;
            cx = (cx < 0) ? 0 : ((cx > Dd - 1) ? Dd - 1 : cx);
            const size_t rb = rb0 + (size_t)cx * BWk;
            float4a a = *(const float4a*)(pw + rb + (size_t)y0c * (Dd * BWk));
            float4a b = *(const float4a*)(pw + rb + (size_t)y1c * (Dd * BWk));
            float v0 = fmaf(fy, b.x - a.x, a.x);
            float v1 = fmaf(fy, b.y - a.y, a.y);
            float v2 = fmaf(fy, b.z - a.z, a.z);
            float v3 = lastk ? 0.f : fmaf(fy, b.w - a.w, a.w);   // k=31 pad = 0
            *(uint2*)&wYb[i * CS + n * NS + k0] = make_uint2(pk2(v0, v1), pk2(v2, v3));
        }
    }
    __syncthreads();

    const int lane = tid & 63;
    const int px   = lane & 15;         // MFMA column = pixel-in-tile
    const int q    = lane >> 4;         // k-slice / C row group
    const int t    = tid >> 6;          // wave id = 16-px tile (0..3)
    const int xt0  = x0 + 16 * t;       // tile's global x base

    // A-frags: A[j][mh] = wY[c=4t+j][n = mh*16 + px][k = 8q..8q+7], loaded once
    bf16x8 A[6][2];
    #pragma unroll
    for (int j = 0; j < 6; ++j) {
        const unsigned short* base = &wYb[(4 * t + j) * CS + q * 8];
        A[j][0] = *(const bf16x8*)&base[px * NS];
        A[j][1] = *(const bf16x8*)&base[(16 + px) * NS];
    }

    // per-pixel x-interp coefficients c_j (2 of 6 nonzero); (xt0+px)&3 == px&3
    const int rx = px & 3;
    const float fx = 0.125f + 0.25f * (float)((rx + 2) & 3);
    const int j0 = (px >> 2) + ((rx < 2) ? 0 : 1);   // 0..4
    float c[6];
    #pragma unroll
    for (int j = 0; j < 6; ++j)
        c[j] = (j == j0) ? (1.f - fx) : ((j == j0 + 1) ? fx : 0.f);

    const int gxb = xt0 + px + q * 8 - 15;           // B element i -> x[gxb + i]
    const bool edge = (bx == 0 && t == 0) || (bx == 3 && t == 3);
    const f32x4 zero = {0.f, 0.f, 0.f, 0.f};

    // store-phase lane roles: instr s covers rows 8t+4s+rr, 16B (4 px) per lane
    const int rr = lane >> 4;           // row within the 4-row group
    const int ii = lane & 15;           // 16B chunk within the 64-px row
    const size_t sb = (size_t)y * 256 + (size_t)x0 + (size_t)(ii * 4);

    #pragma unroll 2
    for (int bc = 0; bc < 32; ++bc) {
        const float* xrow = x + ((size_t)bc * 256 + y) * 256;

        // B-frag: Hankel column px, k-slice q (direct from global, L2-hot)
        float4a v0, v1;
        if (!edge) {
            v0 = *(const float4a*)(xrow + gxb);
            v1 = *(const float4a*)(xrow + gxb + 4);
        } else {
            float tv[8];
            #pragma unroll
            for (int i = 0; i < 8; ++i) {
                int gx = gxb + i;
                tv[i] = ((unsigned)gx < 256u) ? xrow[gx] : 0.f;
            }
            v0 = *(float4a*)&tv[0]; v1 = *(float4a*)&tv[4];
        }
        union { unsigned u[4]; bf16x8 v; } bb;
        bb.u[0] = pk2(v0.x, v0.y);
        bb.u[1] = pk2(v0.z, v0.w);
        bb.u[2] = pk2(v1.x, v1.y);
        bb.u[3] = pk2(v1.z, v1.w);
        const bf16x8 B = bb.v;

        float* tl = tile[bc & 1];
        #pragma unroll
        for (int mh = 0; mh < 2; ++mh) {
            f32x4 acc = zero;
            #pragma unroll
            for (int j = 0; j < 6; ++j) {
                f32x4 g = __builtin_amdgcn_mfma_f32_16x16x32_bf16(
                              A[j][mh], B, zero, 0, 0, 0);
                acc += g * c[j];               // x-interp blend, exact in f32
            }
            // C layout: col = px, row = 4q + reg -> n = mh*16 + 4q + reg
            float* w = tl + (mh * 16 + q * 4) * RS + 16 * t + px;
            w[0]      = acc.x;
            w[RS]     = acc.y;
            w[2 * RS] = acc.z;
            w[3 * RS] = acc.w;
        }
        lds_barrier();   // LDS visibility only; nt stores keep draining async

        // store phase: two dwordx4 wave-stores (rows 8t..8t+7 in 4-row groups)
        const float* ts = tile[bc & 1];
        #pragma unroll
        for (int s = 0; s < 2; ++s) {
            const int row = t * 8 + s * 4 + rr;          // n index (0..31)
            f32x4 v = *(const f32x4*)&ts[row * RS + ii * 4];
            f32x4* dst = (f32x4*)(out + (size_t)(bc * 32 + row) * 65536 + sb);
            __builtin_nontemporal_store(v, dst);
        }
    }
}

extern "C" void kernel_launch(void* const* d_in, const int* in_sizes, int n_in,
                              void* d_out, int out_size, void* d_ws, size_t ws_size,
                              hipStream_t stream) {
    const float* pw = (const float*)d_in[0];   // pre_weights [32,4096,31]
    const float* x  = (const float*)d_in[1];   // x [4,8,256,256] -> [32,256,256]
    float* out = (float*)d_out;                // [32,32,256,256] f32

    dim3 grid(1024, 1, 1);
    dim3 block(NTH, 1, 1);
    band_mfma<<<grid, block, 0, stream>>>(pw, x, out);
}

// Round 16
// 70.149 us; speedup vs baseline: 3.0567x; 1.0001x over previous
//
#include <hip/hip_runtime.h>
#include <hip/hip_bf16.h>

#define Dd   64
#define BWk  31
#define NTH  256
#define NS   32                 // wYb k-stride (bf16 units): 64B rows (A-frags load once)
#define CS   (32 * NS)          // per-coarse-col stride = 1024 shorts
#define NCOL 18                 // coarse cols staged per block (64px -> 16 + 2 border)
#define RS   64                 // result-tile row stride (floats)

typedef float  f32x4   __attribute__((ext_vector_type(4)));
typedef short  bf16x8  __attribute__((ext_vector_type(8)));
typedef float  float4a __attribute__((ext_vector_type(4), aligned(4)));

__device__ __forceinline__ unsigned pk2(float lo, float hi) {
    __hip_bfloat162 h = __float22bfloat162_rn(make_float2(lo, hi));
    union { __hip_bfloat162 h; unsigned u; } c; c.h = h; return c.u;
}

// barrier that only waits for LDS ops (NOT the global store / load queues).
__device__ __forceinline__ void lds_barrier() {
    asm volatile("s_waitcnt lgkmcnt(0)" ::: "memory");
    __builtin_amdgcn_s_barrier();
    __builtin_amdgcn_sched_barrier(0);
}

__global__ __launch_bounds__(NTH, 3)
void band_mfma(const float* __restrict__ pw,
               const float* __restrict__ x,
               float* __restrict__ out)
{
    // y-interpolated coarse weights, bf16: [c=18][n=32][k=32 (k31=0)]
    __shared__ unsigned short wYb[NCOL * CS];        // 36864 B
    // double-buffered result tile: [32 n][64 px], row stride 64
    __shared__ float tile[2][32 * RS];               // 2 x 8192 B (total 53248 B)

    const int tid = threadIdx.x;

    // --- XCD y-banding swizzle, bx-FASTEST within band (vs R15 bx-slowest) ---
    // XCD g owns the contiguous y-band [32g, 32g+32). Within the band, bx
    // cycles fastest so the ~96 co-resident blocks per XCD = 4bx x 24
    // consecutive y: all 16 wave-bursts of each 4KB DRAM page (4bx x 4y of a
    // plane) are issued by concurrently-running, phase-locked blocks ->
    // pages fill in one visit instead of >=4 episodes.
    const unsigned id   = blockIdx.x;        // 0..1023
    const unsigned xcd  = id & 7u;
    const unsigned slot = id >> 3;           // 0..127
    const int bx = (int)(slot & 3u);         // fastest
    const int y  = (int)(xcd * 32u + (slot >> 2));
    const int x0 = bx * 64;

    // exact scale-4 half-pixel y interpolation (validated rounds 1-15)
    const int yq = y >> 2, ry = y & 3;
    const int y0i = yq + ((ry < 2) ? -1 : 0);
    const float fy = 0.125f + 0.25f * (float)((ry + 2) & 3);
    const int y0c = (y0i < 0) ? 0 : y0i;
    const int y1c = (y0i + 1 > Dd - 1) ? Dd - 1 : (y0i + 1);
    const int cxb = (x0 >> 2) - 1;      // leftmost coarse col staged

    // ---- stage wYb: thread task = (n = tid>>3, k0 = (tid&7)*4) over 18 cols ----
    {
        const int n  = tid >> 3;            // 0..31
        const int k0 = (tid & 7) << 2;      // 0,4,...,28
        const bool lastk = (k0 == 28);
        const size_t rb0 = ((size_t)n * 4096) * BWk + k0;
        #pragma unroll 6
        for (int i = 0; i < NCOL; ++i) {
            int cx = cxb + i;
            cx = (cx < 0) ? 0 : ((cx > Dd - 1) ? Dd - 1 : cx);
            const size_t rb = rb0 + (size_t)cx * BWk;
            float4a a = *(const float4a*)(pw + rb + (size_t)y0c * (Dd * BWk));
            float4a b = *(const float4a*)(pw + rb + (size_t)y1c * (Dd * BWk));
            float v0 = fmaf(fy, b.x - a.x, a.x);
            float v1 = fmaf(fy, b.y - a.y, a.y);
            float v2 = fmaf(fy, b.z - a.z, a.z);
            float v3 = lastk ? 0.f : fmaf(fy, b.w - a.w, a.w);   // k=31 pad = 0
            *(uint2*)&wYb[i * CS + n * NS + k0] = make_uint2(pk2(v0, v1), pk2(v2, v3));
        }
    }
    __syncthreads();

    const int lane = tid & 63;
    const int px   = lane & 15;         // MFMA column = pixel-in-tile
    const int q    = lane >> 4;         // k-slice / C row group
    const int t    = tid >> 6;          // wave id = 16-px tile (0..3)
    const int xt0  = x0 + 16 * t;       // tile's global x base

    // A-frags: A[j][mh] = wY[c=4t+j][n = mh*16 + px][k = 8q..8q+7], loaded once
    bf16x8 A[6][2];
    #pragma unroll
    for (int j = 0; j < 6; ++j) {
        const unsigned short* base = &wYb[(4 * t + j) * CS + q * 8];
        A[j][0] = *(const bf16x8*)&base[px * NS];
        A[j][1] = *(const bf16x8*)&base[(16 + px) * NS];
    }

    // per-pixel x-interp coefficients c_j (2 of 6 nonzero); (xt0+px)&3 == px&3
    const int rx = px & 3;
    const float fx = 0.125f + 0.25f * (float)((rx + 2) & 3);
    const int j0 = (px >> 2) + ((rx < 2) ? 0 : 1);   // 0..4
    float c[6];
    #pragma unroll
    for (int j = 0; j < 6; ++j)
        c[j] = (j == j0) ? (1.f - fx) : ((j == j0 + 1) ? fx : 0.f);

    const int gxb = xt0 + px + q * 8 - 15;           // B element i -> x[gxb + i]
    const bool edge = (bx == 0 && t == 0) || (bx == 3 && t == 3);
    const f32x4 zero = {0.f, 0.f, 0.f, 0.f};

    // store-phase lane roles: instr s covers rows 8t+4s+rr, 16B (4 px) per lane
    const int rr = lane >> 4;           // row within the 4-row group
    const int ii = lane & 15;           // 16B chunk within the 64-px row
    const size_t sb = (size_t)y * 256 + (size_t)x0 + (size_t)(ii * 4);

    #pragma unroll 2
    for (int bc = 0; bc < 32; ++bc) {
        const float* xrow = x + ((size_t)bc * 256 + y) * 256;

        // B-frag: Hankel column px, k-slice q (direct from global, L2-hot)
        float4a v0, v1;
        if (!edge) {
            v0 = *(const float4a*)(xrow + gxb);
            v1 = *(const float4a*)(xrow + gxb + 4);
        } else {
            float tv[8];
            #pragma unroll
            for (int i = 0; i < 8; ++i) {
                int gx = gxb + i;
                tv[i] = ((unsigned)gx < 256u) ? xrow[gx] : 0.f;
            }
            v0 = *(float4a*)&tv[0]; v1 = *(float4a*)&tv[4];
        }
        union { unsigned u[4]; bf16x8 v; } bb;
        bb.u[0] = pk2(v0.x, v0.y);
        bb.u[1] = pk2(v0.z, v0.w);
        bb.u[2] = pk2(v1.x, v1.y);
        bb.u[3] = pk2(v1.z, v1.w);
        const bf16x8 B = bb.v;

        float* tl = tile[bc & 1];
        #pragma unroll
        for (int mh = 0; mh < 2; ++mh) {
            f32x4 acc = zero;
            #pragma unroll
            for (int j = 0; j < 6; ++j) {
                f32x4 g = __builtin_amdgcn_mfma_f32_16x16x32_bf16(
                              A[j][mh], B, zero, 0, 0, 0);
                acc += g * c[j];               // x-interp blend, exact in f32
            }
            // C layout: col = px, row = 4q + reg -> n = mh*16 + 4q + reg
            float* w = tl + (mh * 16 + q * 4) * RS + 16 * t + px;
            w[0]      = acc.x;
            w[RS]     = acc.y;
            w[2 * RS] = acc.z;
            w[3 * RS] = acc.w;
        }
        lds_barrier();   // LDS visibility only; nt stores keep draining async

        // store phase: two dwordx4 wave-stores (rows 8t..8t+7 in 4-row groups)
        const float* ts = tile[bc & 1];
        #pragma unroll
        for (int s = 0; s < 2; ++s) {
            const int row = t * 8 + s * 4 + rr;          // n index (0..31)
            f32x4 v = *(const f32x4*)&ts[row * RS + ii * 4];
            f32x4* dst = (f32x4*)(out + (size_t)(bc * 32 + row) * 65536 + sb);
            __builtin_nontemporal_store(v, dst);
        }
    }
}

extern "C" void kernel_launch(void* const* d_in, const int* in_sizes, int n_in,
                              void* d_out, int out_size, void* d_ws, size_t ws_size,
                              hipStream_t stream) {
    const float* pw = (const float*)d_in[0];   // pre_weights [32,4096,31]
    const float* x  = (const float*)d_in[1];   // x [4,8,256,256] -> [32,256,256]
    float* out = (float*)d_out;                // [32,32,256,256] f32

    dim3 grid(1024, 1, 1);
    dim3 block(NTH, 1, 1);
    band_mfma<<<grid, block, 0, stream>>>(pw, x, out);
}